// Round 6
// baseline (295.804 us; speedup 1.0000x reference)
//
#include <hip/hip_runtime.h>

typedef unsigned short u16;
typedef __attribute__((ext_vector_type(8))) __bf16 bf16x8;
typedef __attribute__((ext_vector_type(4))) float f32x4;
typedef __attribute__((ext_vector_type(4))) u16 u16x4;

#define NB 4
#define NQ 2048
#define NKV 1024
#define NH 16
#define DH 64
#define DIN 1024
#define DCTX 768
#define NEGBIG -1e30f
#define QSC 0.180336881f   // 0.125 * log2(e): softmax scale folded into Q, exp -> exp2

__device__ inline u16 f2bf(float f) {
  unsigned u = __builtin_bit_cast(unsigned, f);
  u += 0x7FFFu + ((u >> 16) & 1u);
  return (u16)(u >> 16);
}

__device__ inline unsigned cvtpk(float lo, float hi) {
  unsigned r;
  asm("v_cvt_pk_bf16_f32 %0, %1, %2" : "=v"(r) : "v"(lo), "v"(hi));
  return r;
}

__device__ inline float exp2a(float x) {  // v_exp_f32 computes 2^x natively
  float r;
  asm("v_exp_f32 %0, %1" : "=v"(r) : "v"(x));
  return r;
}

// ---------------- mask dtype detection + bias build ----------------
__global__ __launch_bounds__(256) void build_bias(const void* __restrict__ mask,
                                                  float* __restrict__ biasg) {
  __shared__ int notInt, notFloat;
  if (threadIdx.x == 0) { notInt = 0; notFloat = 0; }
  __syncthreads();
  const unsigned* mw = (const unsigned*)mask;
  int bad_i = 0, bad_f = 0;
#pragma unroll
  for (int e = 0; e < 4; e++) {
    unsigned v = mw[threadIdx.x * 4 + e];
    if (v > 1u) bad_i = 1;
    if (v != 0u && v != 0x3f800000u) bad_f = 1;
  }
  if (bad_i) atomicOr(&notInt, 1);
  if (bad_f) atomicOr(&notFloat, 1);
  __syncthreads();
  const int isInt = !notInt, isFloat = !notFloat;
  for (int i = threadIdx.x; i < NB * NKV; i += 256) {
    bool on;
    if (isInt)        on = ((const int*)mask)[i] != 0;
    else if (isFloat) on = ((const float*)mask)[i] != 0.f;
    else              on = ((const unsigned char*)mask)[i] != 0;
    biasg[i] = on ? 0.f : NEGBIG;
  }
}

// ---------------- fp32 -> bf16 elementwise ----------------
__global__ __launch_bounds__(256) void cvt_bf16(const float* __restrict__ in,
                                                u16* __restrict__ out, int n) {
  int i = (blockIdx.x * 256 + threadIdx.x) * 4;
  if (i >= n) return;
  float4 v = *(const float4*)(in + i);
  u16x4 o = { f2bf(v.x), f2bf(v.y), f2bf(v.z), f2bf(v.w) };
  *(u16x4*)(out + i) = o;
}

// ---------------- W[K][N] fp32 -> Wt[N][K] bf16 ----------------
__global__ __launch_bounds__(256) void transpose_cvt(const float* __restrict__ W,
                                                     u16* __restrict__ Wt, int K, int N) {
  __shared__ float tile[32][33];
  int n0 = blockIdx.x * 32, k0 = blockIdx.y * 32;
  int tx = threadIdx.x & 31, ty = threadIdx.x >> 5;
#pragma unroll
  for (int i = 0; i < 32; i += 8)
    tile[ty + i][tx] = W[(size_t)(k0 + ty + i) * N + n0 + tx];
  __syncthreads();
#pragma unroll
  for (int i = 0; i < 32; i += 8)
    Wt[(size_t)(n0 + ty + i) * K + k0 + tx] = f2bf(tile[tx][ty + i]);
}

// ---------------- V^T: kvb V-half [4096][2048 cols 1024..2047] -> vtg [(b,h),d,j] ----------------
__global__ __launch_bounds__(256) void vtrans(const u16* __restrict__ kvb, u16* __restrict__ vtg) {
  __shared__ __align__(16) u16 tile[64][72];
  const int t = threadIdx.x;
  const int jt = blockIdx.x, bh = blockIdx.y;
  const int b = bh >> 4, h = bh & 15;
  const int j0 = jt * 64;
  const int jl = t >> 2, c2 = t & 3;
  const u16* src = kvb + (size_t)(b * 1024 + j0 + jl) * 2048 + 1024 + h * 64 + c2 * 16;
  *(int4*)&tile[jl][c2 * 16]     = *(const int4*)(src);
  *(int4*)&tile[jl][c2 * 16 + 8] = *(const int4*)(src + 8);
  __syncthreads();
  const int dl = t >> 2;
  union { u16 e[16]; int4 q[2]; } pk;
#pragma unroll
  for (int e = 0; e < 16; e++) pk.e[e] = tile[c2 * 16 + e][dl];
  u16* dst = vtg + (size_t)(bh * 64 + dl) * 1024 + j0 + c2 * 16;
  *(int4*)dst       = pk.q[0];
  *(int4*)(dst + 8) = pk.q[1];
}

// ---------------- bf16 GEMM: C[M][N] = A * Bt^T ----------------
// BM=256 BN=128 BK=64, 512 thr = 8 waves (4 wr x 2 wc, 64x64 per wave), 2-phase dbuf,
// chunk-XOR swizzle c^(row&7) (pre-swizzled global source + swizzled ds_read).
// mode: 0 = f32 + bias, 1 = bf16, 2 = bf16 * QSC
__global__ __launch_bounds__(512) void gemm256(const u16* __restrict__ A,
                                               const u16* __restrict__ Bt,
                                               void* __restrict__ Cout,
                                               const float* __restrict__ bias,
                                               int N, int K, int mode) {
  __shared__ __align__(16) u16 As[2][256 * 64];   // 64 KB
  __shared__ __align__(16) u16 Bs[2][128 * 64];   // 32 KB
  const int t = threadIdx.x, w = t >> 6, l = t & 63, g = l >> 4, m16 = l & 15;
  const int brow = blockIdx.y * 256, bcol = blockIdx.x * 128;
  const int wr = w >> 1, wc = w & 1;
  const int nk = K >> 6;
  const int srow = t >> 3;        // 0..63 staging row within 64-row round
  const int sc   = t & 7;         // chunk position 0..7
  f32x4 acc[4][4] = {};

#define STAGE(ks, bsel)                                                              \
  {                                                                                  \
    int k0_ = (ks) << 6;                                                             \
    _Pragma("unroll")                                                                \
    for (int r = 0; r < 4; r++) {                                                    \
      int row = r * 64 + srow;                                                       \
      int cs = sc ^ (row & 7);                                                       \
      const u16* ga = A + (size_t)(brow + row) * K + k0_ + cs * 8;                   \
      __builtin_amdgcn_global_load_lds(                                              \
          (const __attribute__((address_space(1))) void*)ga,                         \
          (__attribute__((address_space(3))) void*)((char*)As + (bsel) * 32768 + r * 8192 + t * 16), \
          16, 0, 0);                                                                 \
    }                                                                                \
    _Pragma("unroll")                                                                \
    for (int r = 0; r < 2; r++) {                                                    \
      int row = r * 64 + srow;                                                       \
      int cs = sc ^ (row & 7);                                                       \
      const u16* gb = Bt + (size_t)(bcol + row) * K + k0_ + cs * 8;                  \
      __builtin_amdgcn_global_load_lds(                                              \
          (const __attribute__((address_space(1))) void*)gb,                         \
          (__attribute__((address_space(3))) void*)((char*)Bs + (bsel) * 16384 + r * 8192 + t * 16), \
          16, 0, 0);                                                                 \
    }                                                                                \
  }

  STAGE(0, 0);
  asm volatile("s_waitcnt vmcnt(0)" ::: "memory");
  asm volatile("s_barrier" ::: "memory");

  for (int ks = 0; ks < nk; ++ks) {
    const int cur = ks & 1;
    if (ks + 1 < nk) STAGE(ks + 1, cur ^ 1);
#pragma unroll
    for (int kh = 0; kh < 2; kh++) {
      bf16x8 af[4], bfr[4];
      const int cp = ((kh * 4 + g) ^ (m16 & 7)) * 8;
#pragma unroll
      for (int m = 0; m < 4; m++)
        af[m] = *(const bf16x8*)(&As[cur][(wr * 64 + m * 16 + m16) * 64 + cp]);
#pragma unroll
      for (int n = 0; n < 4; n++)
        bfr[n] = *(const bf16x8*)(&Bs[cur][(wc * 64 + n * 16 + m16) * 64 + cp]);
#pragma unroll
      for (int m = 0; m < 4; m++)
#pragma unroll
        for (int n = 0; n < 4; n++)
          acc[m][n] = __builtin_amdgcn_mfma_f32_16x16x32_bf16(af[m], bfr[n], acc[m][n], 0, 0, 0);
    }
    asm volatile("s_waitcnt vmcnt(0)" ::: "memory");
    asm volatile("s_barrier" ::: "memory");
  }
#undef STAGE

#pragma unroll
  for (int m = 0; m < 4; m++) {
    int grow = brow + wr * 64 + m * 16 + g * 4;
#pragma unroll
    for (int n = 0; n < 4; n++) {
      int gcol = bcol + wc * 64 + n * 16 + m16;
#pragma unroll
      for (int r = 0; r < 4; r++) {
        size_t off = (size_t)(grow + r) * N + gcol;
        if (mode == 0)      ((float*)Cout)[off] = acc[m][n][r] + bias[gcol];
        else if (mode == 1) ((u16*)Cout)[off] = f2bf(acc[m][n][r]);
        else                ((u16*)Cout)[off] = f2bf(acc[m][n][r] * QSC);
      }
    }
  }
}

// ---------------- flash attention ----------------
// swapped QK^T, fixed-max softmax (Q pre-scaled, p = 2^(s+bias)); K and V^T both staged
// via global_load_lds with pre-swizzled source; dbuf, stage issued at tile top.
// grid (32 qtiles, 16 heads, 4 batch), 256 thr = 4 waves, QBLK=64 (16 rows/wave), KVBLK=64
__global__ __launch_bounds__(256) void attn(const u16* __restrict__ Q, const u16* __restrict__ Kb,
                                            const u16* __restrict__ Vt_g,
                                            const float* __restrict__ biasg,
                                            u16* __restrict__ O) {
  const int qt = blockIdx.x, h = blockIdx.y, b = blockIdx.z;
  const int t = threadIdx.x, w = t >> 6, l = t & 63, g = l >> 4, m16 = l & 15;
  const int bh = b * NH + h;

  __shared__ __align__(16) u16 Kl[2][4096];       // [j][d-chunks], pos p holds data chunk p^(j&7)
  __shared__ __align__(16) u16 Vt[2][4096];       // [d][j-chunks], pos p holds data chunk p^(d&7)
  __shared__ __align__(16) unsigned Pl[4][16 * 36];
  __shared__ float biasl[NKV];

  for (int i = t; i < NKV; i += 256) biasl[i] = biasg[(size_t)b * NKV + i];

  const int qrow = qt * 64 + w * 16 + m16;
  const u16* qp = Q + (size_t)(b * NQ + qrow) * DIN + h * DH;
  bf16x8 qA0 = *(const bf16x8*)(qp + g * 8);
  bf16x8 qA1 = *(const bf16x8*)(qp + 32 + g * 8);

  f32x4 oA[4] = {};
  float lA = 0.f;

#define STAGE_K(j0, bsel)                                                     \
  {                                                                           \
    _Pragma("unroll")                                                         \
    for (int n = 0; n < 2; n++) {                                             \
      int j_ = n * 32 + (t >> 3);                                             \
      int c_ = (t & 7) ^ (j_ & 7);                                            \
      const u16* gk = Kb + (size_t)(b * NKV + (j0) + j_) * 2048 + h * DH + c_ * 8; \
      __builtin_amdgcn_global_load_lds(                                       \
          (const __attribute__((address_space(1))) void*)gk,                  \
          (__attribute__((address_space(3))) void*)((char*)Kl + (bsel) * 8192 + n * 4096 + t * 16), \
          16, 0, 0);                                                          \
    }                                                                         \
  }
#define STAGE_V(j0, bsel)                                                     \
  {                                                                           \
    _Pragma("unroll")                                                         \
    for (int n = 0; n < 2; n++) {                                             \
      int d_ = n * 32 + (t >> 3);                                             \
      int c_ = (t & 7) ^ (d_ & 7);                                            \
      const u16* gv = Vt_g + (size_t)(bh * 64 + d_) * 1024 + (j0) + c_ * 8;   \
      __builtin_amdgcn_global_load_lds(                                       \
          (const __attribute__((address_space(1))) void*)gv,                  \
          (__attribute__((address_space(3))) void*)((char*)Vt + (bsel) * 8192 + n * 4096 + t * 16), \
          16, 0, 0);                                                          \
    }                                                                         \
  }

  STAGE_K(0, 0);
  STAGE_V(0, 0);
  asm volatile("s_waitcnt vmcnt(0) lgkmcnt(0)" ::: "memory");
  asm volatile("s_barrier" ::: "memory");

  for (int it = 0; it < 16; ++it) {
    const int cur = it & 1, nxt = cur ^ 1;
    const int j0 = it * 64;
    if (it + 1 < 16) {
      STAGE_K(j0 + 64, nxt);
      STAGE_V(j0 + 64, nxt);
    }

    // ---- QK^T (swapped): lane holds S^T[j][i], i=m16 ----
    f32x4 sA[4];
#pragma unroll
    for (int jt = 0; jt < 4; jt++) {
      int jr = jt * 16 + m16;
      const u16* krow = &Kl[cur][jr * 64];
      bf16x8 kf0 = *(const bf16x8*)(krow + ((g ^ (jr & 7)) * 8));
      bf16x8 kf1 = *(const bf16x8*)(krow + (((4 + g) ^ (jr & 7)) * 8));
      f32x4 z = {};
      f32x4 t0 = __builtin_amdgcn_mfma_f32_16x16x32_bf16(kf0, qA0, z, 0, 0, 0);
      sA[jt]   = __builtin_amdgcn_mfma_f32_16x16x32_bf16(kf1, qA1, t0, 0, 0, 0);
    }
    float4 b4[4];
#pragma unroll
    for (int jt = 0; jt < 4; jt++) b4[jt] = *(const float4*)&biasl[j0 + jt * 16 + g * 4];

    unsigned* plw = &Pl[w][0];
#pragma unroll
    for (int jt = 0; jt < 4; jt++) {
      float p0 = exp2a(sA[jt][0] + b4[jt].x);
      float p1 = exp2a(sA[jt][1] + b4[jt].y);
      float p2 = exp2a(sA[jt][2] + b4[jt].z);
      float p3 = exp2a(sA[jt][3] + b4[jt].w);
      lA += (p0 + p1) + (p2 + p3);
      uint2 u; u.x = cvtpk(p0, p1); u.y = cvtpk(p2, p3);
      *(uint2*)&plw[m16 * 36 + jt * 8 + 2 * g] = u;
    }
    asm volatile("" ::: "memory");
    bf16x8 pf0 = *(const bf16x8*)&plw[m16 * 36 + 4 * g];
    bf16x8 pf1 = *(const bf16x8*)&plw[m16 * 36 + 16 + 4 * g];
#pragma unroll
    for (int dt = 0; dt < 4; dt++) {
      int d = dt * 16 + m16;
      const u16* vrow = &Vt[cur][d * 64];
      bf16x8 vf0 = *(const bf16x8*)(vrow + ((g ^ (d & 7)) * 8));
      bf16x8 vf1 = *(const bf16x8*)(vrow + (((4 + g) ^ (d & 7)) * 8));
      oA[dt] = __builtin_amdgcn_mfma_f32_16x16x32_bf16(pf0, vf0, oA[dt], 0, 0, 0);
      oA[dt] = __builtin_amdgcn_mfma_f32_16x16x32_bf16(pf1, vf1, oA[dt], 0, 0, 0);
    }
    asm volatile("s_waitcnt vmcnt(0)" ::: "memory");
    asm volatile("s_barrier" ::: "memory");
  }
#undef STAGE_K
#undef STAGE_V

  lA += __shfl_xor(lA, 16); lA += __shfl_xor(lA, 32);
  float invA[4];
#pragma unroll
  for (int r = 0; r < 4; r++) invA[r] = 1.f / __shfl(lA, g * 4 + r);
  u16* op = O + (size_t)(b * NQ + qt * 64 + w * 16) * DIN + h * DH;
#pragma unroll
  for (int dt = 0; dt < 4; dt++)
#pragma unroll
    for (int r = 0; r < 4; r++)
      op[(size_t)(g * 4 + r) * DIN + dt * 16 + m16] = f2bf(oA[dt][r] * invA[r]);
}

// ---------------- launcher ----------------
extern "C" void kernel_launch(void* const* d_in, const int* in_sizes, int n_in,
                              void* d_out, int out_size, void* d_ws, size_t ws_size,
                              hipStream_t stream) {
  const float* x   = (const float*)d_in[0];
  const float* ctx = (const float*)d_in[1];
  const void*  mask = (const void*)d_in[2];
  const float* Wq  = (const float*)d_in[3];
  const float* Wk  = (const float*)d_in[4];
  const float* Wv  = (const float*)d_in[5];
  const float* Wo  = (const float*)d_in[6];
  const float* bo  = (const float*)d_in[7];
  float* out = (float*)d_out;

  char* ws = (char*)d_ws;
  u16* xb   = (u16*)(ws);                  // [8192][1024] bf16 (reused as ab)
  u16* cb   = (u16*)(ws + 16777216);       // [4096][768]
  u16* wqt  = (u16*)(ws + 23068672);       // [1024][1024]
  u16* wkv  = (u16*)(ws + 25165824);       // [2048][768]  (Wk^T | Wv^T)
  u16* wot  = (u16*)(ws + 28311552);       // [1024][1024]
  u16* qb   = (u16*)(ws + 30408704);       // [8192][1024]
  u16* kvb  = (u16*)(ws + 47185920);       // [4096][2048] (K | V)
  u16* vtg  = (u16*)(ws + 16777216);       // [(b,h)*64+d][1024] — overlaps cb/wqt (dead by vtrans)
  float* biasg = (float*)(ws + 63963136);  // [4][1024]
  u16* ab   = xb;

  build_bias<<<1, 256, 0, stream>>>(mask, biasg);
  cvt_bf16<<<8192, 256, 0, stream>>>(x, xb, 8388608);
  cvt_bf16<<<3072, 256, 0, stream>>>(ctx, cb, 3145728);
  transpose_cvt<<<dim3(32, 32), 256, 0, stream>>>(Wq, wqt, 1024, 1024);
  transpose_cvt<<<dim3(32, 24), 256, 0, stream>>>(Wk, wkv, 768, 1024);
  transpose_cvt<<<dim3(32, 24), 256, 0, stream>>>(Wv, wkv + 1024 * 768, 768, 1024);
  transpose_cvt<<<dim3(32, 32), 256, 0, stream>>>(Wo, wot, 1024, 1024);

  gemm256<<<dim3(8, 32), 512, 0, stream>>>(xb, wqt, qb, nullptr, 1024, 1024, 2);   // Q (pre-scaled)
  gemm256<<<dim3(16, 16), 512, 0, stream>>>(cb, wkv, kvb, nullptr, 2048, 768, 1);  // K|V

  vtrans<<<dim3(16, 64), 256, 0, stream>>>(kvb, vtg);

  attn<<<dim3(32, 16, 4), 256, 0, stream>>>(qb, kvb, vtg, biasg, ab);

  gemm256<<<dim3(8, 32), 512, 0, stream>>>(ab, wot, out, bo, 1024, 1024, 0);       // O + bias
}

// Round 7
// 271.035 us; speedup vs baseline: 1.0914x; 1.0914x over previous
//
#include <hip/hip_runtime.h>

typedef unsigned short u16;
typedef __attribute__((ext_vector_type(8))) __bf16 bf16x8;
typedef __attribute__((ext_vector_type(4))) float f32x4;
typedef __attribute__((ext_vector_type(16))) float f32x16;
typedef __attribute__((ext_vector_type(4))) u16 u16x4;

#define NB 4
#define NQ 2048
#define NKV 1024
#define NH 16
#define DH 64
#define DIN 1024
#define DCTX 768
#define NEGBIG -1e30f
#define QSC 0.180336881f   // 0.125 * log2(e): softmax scale folded into Q, exp -> exp2

__device__ inline u16 f2bf(float f) {
  unsigned u = __builtin_bit_cast(unsigned, f);
  u += 0x7FFFu + ((u >> 16) & 1u);
  return (u16)(u >> 16);
}

__device__ inline unsigned cvtpk(float lo, float hi) {
  unsigned r;
  asm("v_cvt_pk_bf16_f32 %0, %1, %2" : "=v"(r) : "v"(lo), "v"(hi));
  return r;
}

__device__ inline float exp2a(float x) {  // v_exp_f32 computes 2^x natively
  float r;
  asm("v_exp_f32 %0, %1" : "=v"(r) : "v"(x));
  return r;
}

// ---------------- mask dtype detection + bias build ----------------
__global__ __launch_bounds__(256) void build_bias(const void* __restrict__ mask,
                                                  float* __restrict__ biasg) {
  __shared__ int notInt, notFloat;
  if (threadIdx.x == 0) { notInt = 0; notFloat = 0; }
  __syncthreads();
  const unsigned* mw = (const unsigned*)mask;
  int bad_i = 0, bad_f = 0;
#pragma unroll
  for (int e = 0; e < 4; e++) {
    unsigned v = mw[threadIdx.x * 4 + e];
    if (v > 1u) bad_i = 1;
    if (v != 0u && v != 0x3f800000u) bad_f = 1;
  }
  if (bad_i) atomicOr(&notInt, 1);
  if (bad_f) atomicOr(&notFloat, 1);
  __syncthreads();
  const int isInt = !notInt, isFloat = !notFloat;
  for (int i = threadIdx.x; i < NB * NKV; i += 256) {
    bool on;
    if (isInt)        on = ((const int*)mask)[i] != 0;
    else if (isFloat) on = ((const float*)mask)[i] != 0.f;
    else              on = ((const unsigned char*)mask)[i] != 0;
    biasg[i] = on ? 0.f : NEGBIG;
  }
}

// ---------------- fp32 -> bf16 elementwise ----------------
__global__ __launch_bounds__(256) void cvt_bf16(const float* __restrict__ in,
                                                u16* __restrict__ out, int n) {
  int i = (blockIdx.x * 256 + threadIdx.x) * 4;
  if (i >= n) return;
  float4 v = *(const float4*)(in + i);
  u16x4 o = { f2bf(v.x), f2bf(v.y), f2bf(v.z), f2bf(v.w) };
  *(u16x4*)(out + i) = o;
}

// ---------------- W[K][N] fp32 -> Wt[N][K] bf16 ----------------
__global__ __launch_bounds__(256) void transpose_cvt(const float* __restrict__ W,
                                                     u16* __restrict__ Wt, int K, int N) {
  __shared__ float tile[32][33];
  int n0 = blockIdx.x * 32, k0 = blockIdx.y * 32;
  int tx = threadIdx.x & 31, ty = threadIdx.x >> 5;
#pragma unroll
  for (int i = 0; i < 32; i += 8)
    tile[ty + i][tx] = W[(size_t)(k0 + ty + i) * N + n0 + tx];
  __syncthreads();
#pragma unroll
  for (int i = 0; i < 32; i += 8)
    Wt[(size_t)(n0 + ty + i) * K + k0 + tx] = f2bf(tile[tx][ty + i]);
}

// ---------------- V^T: kvb V-half [4096][2048 cols 1024..2047] -> vtg [(b,h),d,j] ----------------
__global__ __launch_bounds__(256) void vtrans(const u16* __restrict__ kvb, u16* __restrict__ vtg) {
  __shared__ __align__(16) u16 tile[64][72];
  const int t = threadIdx.x;
  const int jt = blockIdx.x, bh = blockIdx.y;
  const int b = bh >> 4, h = bh & 15;
  const int j0 = jt * 64;
  const int jl = t >> 2, c2 = t & 3;
  const u16* src = kvb + (size_t)(b * 1024 + j0 + jl) * 2048 + 1024 + h * 64 + c2 * 16;
  *(int4*)&tile[jl][c2 * 16]     = *(const int4*)(src);
  *(int4*)&tile[jl][c2 * 16 + 8] = *(const int4*)(src + 8);
  __syncthreads();
  const int dl = t >> 2;
  union { u16 e[16]; int4 q[2]; } pk;
#pragma unroll
  for (int e = 0; e < 16; e++) pk.e[e] = tile[c2 * 16 + e][dl];
  u16* dst = vtg + (size_t)(bh * 64 + dl) * 1024 + j0 + c2 * 16;
  *(int4*)dst       = pk.q[0];
  *(int4*)(dst + 8) = pk.q[1];
}

// ---------------- bf16 GEMM: C[M][N] = A[M][K] * Bt[N][K]^T (R3-proven m97 structure) ----------------
// mode: 0 = f32 + bias, 1 = bf16, 2 = bf16 * QSC
template<int MODE>
__global__ __launch_bounds__(256) void gemm_bt(const u16* __restrict__ A,
                                               const u16* __restrict__ Bt,
                                               void* __restrict__ Cout,
                                               const float* __restrict__ bias,
                                               int M, int N, int K) {
  __shared__ __align__(16) u16 As[2][128 * 32];
  __shared__ __align__(16) u16 Bs[2][128 * 32];
  const int t = threadIdx.x, w = t >> 6, l = t & 63, g = l >> 4, m16 = l & 15;
  const int brow = blockIdx.y * 128, bcol = blockIdx.x * 128;
  const int wr = w >> 1, wc = w & 1;
  const int r_a = t >> 2;
  const int kb  = (t & 3) * 8;
  const int nk = K >> 5;
  f32x4 acc[4][4] = {};

#define G_STAGE(ks, bsel)                                                              \
  {                                                                                    \
    int k0_ = (ks) << 5;                                                               \
    _Pragma("unroll")                                                                  \
    for (int i = 0; i < 2; i++) {                                                      \
      const u16* ga = A + (size_t)(brow + i * 64 + r_a) * K + k0_ + kb;                \
      __builtin_amdgcn_global_load_lds(                                                \
          (const __attribute__((address_space(1))) void*)ga,                           \
          (__attribute__((address_space(3))) void*)((char*)As + (bsel) * 8192 + i * 4096 + w * 1024), \
          16, 0, 0);                                                                   \
      const u16* gb = Bt + (size_t)(bcol + i * 64 + r_a) * K + k0_ + kb;               \
      __builtin_amdgcn_global_load_lds(                                                \
          (const __attribute__((address_space(1))) void*)gb,                           \
          (__attribute__((address_space(3))) void*)((char*)Bs + (bsel) * 8192 + i * 4096 + w * 1024), \
          16, 0, 0);                                                                   \
    }                                                                                  \
  }

  G_STAGE(0, 0);
  asm volatile("s_waitcnt vmcnt(0)" ::: "memory");
  __builtin_amdgcn_s_barrier();

  for (int ks = 0; ks < nk; ++ks) {
    const int cur = ks & 1;
    bf16x8 af[4], bfr[4];
#pragma unroll
    for (int m = 0; m < 4; m++)
      af[m] = *(const bf16x8*)(&As[cur][(wr * 64 + m * 16 + m16) * 32 + g * 8]);
#pragma unroll
    for (int n = 0; n < 4; n++)
      bfr[n] = *(const bf16x8*)(&Bs[cur][(wc * 64 + n * 16 + m16) * 32 + g * 8]);
    if (ks + 1 < nk) G_STAGE(ks + 1, cur ^ 1);
#pragma unroll
    for (int m = 0; m < 4; m++)
#pragma unroll
      for (int n = 0; n < 4; n++)
        acc[m][n] = __builtin_amdgcn_mfma_f32_16x16x32_bf16(af[m], bfr[n], acc[m][n], 0, 0, 0);
    asm volatile("s_waitcnt vmcnt(0)" ::: "memory");
    __builtin_amdgcn_s_barrier();
  }
#undef G_STAGE

#pragma unroll
  for (int m = 0; m < 4; m++) {
    int grow = brow + wr * 64 + m * 16 + g * 4;
#pragma unroll
    for (int n = 0; n < 4; n++) {
      int gcol = bcol + wc * 64 + n * 16 + m16;
#pragma unroll
      for (int r = 0; r < 4; r++) {
        size_t off = (size_t)(grow + r) * N + gcol;
        if (MODE == 0)      ((float*)Cout)[off] = acc[m][n][r] + bias[gcol];
        else if (MODE == 1) ((u16*)Cout)[off] = f2bf(acc[m][n][r]);
        else                ((u16*)Cout)[off] = f2bf(acc[m][n][r] * QSC);
      }
    }
  }
}

// ---------------- flash attention, 32x32x16 MFMA, in-register P (no P-LDS) ----------------
// swapped QK^T: lane holds S^T[j][i=l&31]; cvt_pk + shfl_xor(32) builds PV A-fragments.
// grid (16 qtiles, 16 heads, 4 batch), 256 thr = 4 waves, QBLK=128 (32 rows/wave), KVBLK=64
__global__ __launch_bounds__(256) void attn(const u16* __restrict__ Q, const u16* __restrict__ Kb,
                                            const u16* __restrict__ Vt_g,
                                            const float* __restrict__ biasg,
                                            u16* __restrict__ O) {
  const int qt = blockIdx.x, h = blockIdx.y, b = blockIdx.z;
  const int t = threadIdx.x, w = t >> 6, l = t & 63;
  const int i32 = l & 31, hi = l >> 5;
  const int bh = b * NH + h;

  __shared__ __align__(16) u16 Kl[2][4096];  // [j][d-chunks], pos p holds data chunk p^(j&7)
  __shared__ __align__(16) u16 Vt[2][4096];  // [d][j-chunks], pos p holds data chunk p^(d&7)
  __shared__ float biasl[NKV];

  for (int i = t; i < NKV; i += 256) biasl[i] = biasg[(size_t)b * NKV + i];

  // Q fragments (B-operand of 32x32x16): lane l -> col i=i32, k-elems d = c*16 + hi*8 + e
  const int qrow = qt * 128 + w * 32 + i32;
  const u16* qp = Q + (size_t)(b * NQ + qrow) * DIN + h * DH;
  bf16x8 qf[4];
#pragma unroll
  for (int c = 0; c < 4; c++) qf[c] = *(const bf16x8*)(qp + c * 16 + hi * 8);

  f32x16 oacc[2] = {};
  float lA = 0.f;

#define STAGE_K(j0, bsel)                                                     \
  {                                                                           \
    _Pragma("unroll")                                                         \
    for (int n = 0; n < 2; n++) {                                             \
      int j_ = n * 32 + (t >> 3);                                             \
      int c_ = (t & 7) ^ (j_ & 7);                                            \
      const u16* gk = Kb + (size_t)(b * NKV + (j0) + j_) * 2048 + h * DH + c_ * 8; \
      __builtin_amdgcn_global_load_lds(                                       \
          (const __attribute__((address_space(1))) void*)gk,                  \
          (__attribute__((address_space(3))) void*)((char*)Kl + (bsel) * 8192 + n * 4096 + t * 16), \
          16, 0, 0);                                                          \
    }                                                                         \
  }
#define STAGE_V(j0, bsel)                                                     \
  {                                                                           \
    _Pragma("unroll")                                                         \
    for (int n = 0; n < 2; n++) {                                             \
      int d_ = n * 32 + (t >> 3);                                             \
      int c_ = (t & 7) ^ (d_ & 7);                                            \
      const u16* gv = Vt_g + (size_t)(bh * 64 + d_) * 1024 + (j0) + c_ * 8;   \
      __builtin_amdgcn_global_load_lds(                                       \
          (const __attribute__((address_space(1))) void*)gv,                  \
          (__attribute__((address_space(3))) void*)((char*)Vt + (bsel) * 8192 + n * 4096 + t * 16), \
          16, 0, 0);                                                          \
    }                                                                         \
  }

  STAGE_K(0, 0);
  STAGE_V(0, 0);
  asm volatile("s_waitcnt vmcnt(0)" ::: "memory");
  __builtin_amdgcn_s_barrier();

  for (int it = 0; it < 16; ++it) {
    const int cur = it & 1, nxt = cur ^ 1;
    const int j0 = it * 64;
    if (it + 1 < 16) {
      STAGE_K(j0 + 64, nxt);
      STAGE_V(j0 + 64, nxt);
    }

    bf16x8 pa[4];   // PV A-fragments: pa[kc], k-elems j = kc*16 + hi*8 + e
#pragma unroll
    for (int jt = 0; jt < 2; jt++) {
      // ---- QK^T 32x32x16: A=K rows j = jt*32+i32, B=Q; S^T[j][i] ----
      f32x16 s = {};
#pragma unroll
      for (int c = 0; c < 4; c++) {
        bf16x8 kf = *(const bf16x8*)&Kl[cur][(jt * 32 + i32) * 64 + (((2 * c + hi) ^ (i32 & 7)) * 8)];
        s = __builtin_amdgcn_mfma_f32_32x32x16_bf16(kf, qf[c], s, 0, 0, 0);
      }
      // lane reg: j = jt*32 + (reg&3) + 8*(reg>>2) + 4*hi, i = i32
      float4 qb4[4];
#pragma unroll
      for (int a = 0; a < 4; a++)
        qb4[a] = *(const float4*)&biasl[j0 + jt * 32 + a * 8 + hi * 4];
      float p[16];
#pragma unroll
      for (int r = 0; r < 16; r++) {
        const float* bq = (const float*)&qb4[r >> 2];
        p[r] = exp2a(s[r] + bq[r & 3]);
      }
#pragma unroll
      for (int r = 0; r < 16; r += 4)
        lA += ((p[r] + p[r + 1]) + (p[r + 2] + p[r + 3]));
      // pack to bf16 pairs: u[a][0] = j {8a+4hi, +1}, u[a][1] = j {8a+4hi+2, +3}
      unsigned u[4][2];
#pragma unroll
      for (int a = 0; a < 4; a++) {
        u[a][0] = cvtpk(p[4 * a], p[4 * a + 1]);
        u[a][1] = cvtpk(p[4 * a + 2], p[4 * a + 3]);
      }
      // half-exchange: build pa[jt*2+cc] covering j = 32jt + 16cc + 8hi + 0..7
#pragma unroll
      for (int cc = 0; cc < 2; cc++) {
        unsigned s0 = hi ? u[2 * cc][0] : u[2 * cc + 1][0];
        unsigned s1 = hi ? u[2 * cc][1] : u[2 * cc + 1][1];
        unsigned r0 = __shfl_xor(s0, 32);
        unsigned r1 = __shfl_xor(s1, 32);
        union { unsigned uu[4]; bf16x8 v; } pw;
        pw.uu[0] = hi ? r0 : u[2 * cc][0];
        pw.uu[1] = hi ? r1 : u[2 * cc][1];
        pw.uu[2] = hi ? u[2 * cc + 1][0] : r0;
        pw.uu[3] = hi ? u[2 * cc + 1][1] : r1;
        pa[jt * 2 + cc] = pw.v;
      }
    }
    // ---- PV 32x32x16: A=pa (rows i=i32), B=V^T (cols d = dt*32+i32) ----
#pragma unroll
    for (int dt = 0; dt < 2; dt++) {
      const int d = dt * 32 + i32;
#pragma unroll
      for (int kc = 0; kc < 4; kc++) {
        bf16x8 vf = *(const bf16x8*)&Vt[cur][d * 64 + (((2 * kc + hi) ^ (i32 & 7)) * 8)];
        oacc[dt] = __builtin_amdgcn_mfma_f32_32x32x16_bf16(pa[kc], vf, oacc[dt], 0, 0, 0);
      }
    }
    asm volatile("s_waitcnt vmcnt(0)" ::: "memory");
    __builtin_amdgcn_s_barrier();
  }
#undef STAGE_K
#undef STAGE_V

  // full row sum: lanes i32 and i32+32 hold complementary j-subsets of row i32
  lA += __shfl_xor(lA, 32);
  float inv = 1.f / lA;   // row i32's inverse
  u16* op = O + (size_t)(b * NQ + qt * 128 + w * 32) * DIN + h * DH;
#pragma unroll
  for (int reg = 0; reg < 16; reg++) {
    const int irow = (reg & 3) + 8 * (reg >> 2) + 4 * hi;
    const float iv = __shfl(inv, irow);   // lane irow holds row irow's inv
#pragma unroll
    for (int dt = 0; dt < 2; dt++)
      op[(size_t)irow * DIN + dt * 32 + i32] = f2bf(oacc[dt][reg] * iv);
  }
}

// ---------------- launcher ----------------
extern "C" void kernel_launch(void* const* d_in, const int* in_sizes, int n_in,
                              void* d_out, int out_size, void* d_ws, size_t ws_size,
                              hipStream_t stream) {
  const float* x   = (const float*)d_in[0];
  const float* ctx = (const float*)d_in[1];
  const void*  mask = (const void*)d_in[2];
  const float* Wq  = (const float*)d_in[3];
  const float* Wk  = (const float*)d_in[4];
  const float* Wv  = (const float*)d_in[5];
  const float* Wo  = (const float*)d_in[6];
  const float* bo  = (const float*)d_in[7];
  float* out = (float*)d_out;

  char* ws = (char*)d_ws;
  u16* xb   = (u16*)(ws);                  // [8192][1024] bf16 (reused as ab)
  u16* cb   = (u16*)(ws + 16777216);       // [4096][768]
  u16* wqt  = (u16*)(ws + 23068672);       // [1024][1024]
  u16* wkv  = (u16*)(ws + 25165824);       // [2048][768]  (Wk^T | Wv^T)
  u16* wot  = (u16*)(ws + 28311552);       // [1024][1024]
  u16* qb   = (u16*)(ws + 30408704);       // [8192][1024]
  u16* kvb  = (u16*)(ws + 47185920);       // [4096][2048] (K | V)
  u16* vtg  = (u16*)(ws + 16777216);       // [(b,h)*64+d][1024] 8.4MB — overlaps cb/wqt (dead by vtrans)
  float* biasg = (float*)(ws + 63963136);  // [4][1024]
  u16* ab   = xb;

  build_bias<<<1, 256, 0, stream>>>(mask, biasg);
  cvt_bf16<<<8192, 256, 0, stream>>>(x, xb, 8388608);
  cvt_bf16<<<3072, 256, 0, stream>>>(ctx, cb, 3145728);
  transpose_cvt<<<dim3(32, 32), 256, 0, stream>>>(Wq, wqt, 1024, 1024);
  transpose_cvt<<<dim3(32, 24), 256, 0, stream>>>(Wk, wkv, 768, 1024);
  transpose_cvt<<<dim3(32, 24), 256, 0, stream>>>(Wv, wkv + 1024 * 768, 768, 1024);
  transpose_cvt<<<dim3(32, 32), 256, 0, stream>>>(Wo, wot, 1024, 1024);

  gemm_bt<2><<<dim3(8, 64), 256, 0, stream>>>(xb, wqt, qb, nullptr, 8192, 1024, 1024);   // Q (pre-scaled)
  gemm_bt<1><<<dim3(16, 32), 256, 0, stream>>>(cb, wkv, kvb, nullptr, 4096, 2048, 768);  // K|V fused

  vtrans<<<dim3(16, 64), 256, 0, stream>>>(kvb, vtg);

  attn<<<dim3(16, 16, 4), 256, 0, stream>>>(qb, kvb, vtg, biasg, ab);

  gemm_bt<0><<<dim3(8, 64), 256, 0, stream>>>(ab, wot, out, bo, 8192, 1024, 1024);       // O + bias
}

// Round 8
// 263.221 us; speedup vs baseline: 1.1238x; 1.0297x over previous
//
#include <hip/hip_runtime.h>

typedef unsigned short u16;
typedef __attribute__((ext_vector_type(8))) __bf16 bf16x8;
typedef __attribute__((ext_vector_type(4))) float f32x4;
typedef __attribute__((ext_vector_type(16))) float f32x16;
typedef __attribute__((ext_vector_type(4))) u16 u16x4;

#define NB 4
#define NQ 2048
#define NKV 1024
#define NH 16
#define DH 64
#define DIN 1024
#define DCTX 768
#define NEGBIG -1e30f
#define QSC 0.180336881f   // 0.125 * log2(e): softmax scale folded into Q, exp -> exp2

__device__ inline u16 f2bf(float f) {
  unsigned u = __builtin_bit_cast(unsigned, f);
  u += 0x7FFFu + ((u >> 16) & 1u);
  return (u16)(u >> 16);
}

__device__ inline unsigned cvtpk(float lo, float hi) {
  unsigned r;
  asm("v_cvt_pk_bf16_f32 %0, %1, %2" : "=v"(r) : "v"(lo), "v"(hi));
  return r;
}

__device__ inline float exp2a(float x) {  // v_exp_f32 computes 2^x natively
  float r;
  asm("v_exp_f32 %0, %1" : "=v"(r) : "v"(x));
  return r;
}

// ---------------- mask dtype detection + bias build ----------------
__global__ __launch_bounds__(256) void build_bias(const void* __restrict__ mask,
                                                  float* __restrict__ biasg) {
  __shared__ int notInt, notFloat;
  if (threadIdx.x == 0) { notInt = 0; notFloat = 0; }
  __syncthreads();
  const unsigned* mw = (const unsigned*)mask;
  int bad_i = 0, bad_f = 0;
#pragma unroll
  for (int e = 0; e < 4; e++) {
    unsigned v = mw[threadIdx.x * 4 + e];
    if (v > 1u) bad_i = 1;
    if (v != 0u && v != 0x3f800000u) bad_f = 1;
  }
  if (bad_i) atomicOr(&notInt, 1);
  if (bad_f) atomicOr(&notFloat, 1);
  __syncthreads();
  const int isInt = !notInt, isFloat = !notFloat;
  for (int i = threadIdx.x; i < NB * NKV; i += 256) {
    bool on;
    if (isInt)        on = ((const int*)mask)[i] != 0;
    else if (isFloat) on = ((const float*)mask)[i] != 0.f;
    else              on = ((const unsigned char*)mask)[i] != 0;
    biasg[i] = on ? 0.f : NEGBIG;
  }
}

// ---------------- fp32 -> bf16 elementwise ----------------
__global__ __launch_bounds__(256) void cvt_bf16(const float* __restrict__ in,
                                                u16* __restrict__ out, int n) {
  int i = (blockIdx.x * 256 + threadIdx.x) * 4;
  if (i >= n) return;
  float4 v = *(const float4*)(in + i);
  u16x4 o = { f2bf(v.x), f2bf(v.y), f2bf(v.z), f2bf(v.w) };
  *(u16x4*)(out + i) = o;
}

// ---------------- W[K][N] fp32 -> Wt[N][K] bf16 ----------------
__global__ __launch_bounds__(256) void transpose_cvt(const float* __restrict__ W,
                                                     u16* __restrict__ Wt, int K, int N) {
  __shared__ float tile[32][33];
  int n0 = blockIdx.x * 32, k0 = blockIdx.y * 32;
  int tx = threadIdx.x & 31, ty = threadIdx.x >> 5;
#pragma unroll
  for (int i = 0; i < 32; i += 8)
    tile[ty + i][tx] = W[(size_t)(k0 + ty + i) * N + n0 + tx];
  __syncthreads();
#pragma unroll
  for (int i = 0; i < 32; i += 8)
    Wt[(size_t)(n0 + ty + i) * K + k0 + tx] = f2bf(tile[tx][ty + i]);
}

// ---------------- V^T: kvb V-half [4096][2048 cols 1024..2047] -> vtg [(b,h),d,j] ----------------
__global__ __launch_bounds__(256) void vtrans(const u16* __restrict__ kvb, u16* __restrict__ vtg) {
  __shared__ __align__(16) u16 tile[64][72];
  const int t = threadIdx.x;
  const int jt = blockIdx.x, bh = blockIdx.y;
  const int b = bh >> 4, h = bh & 15;
  const int j0 = jt * 64;
  const int jl = t >> 2, c2 = t & 3;
  const u16* src = kvb + (size_t)(b * 1024 + j0 + jl) * 2048 + 1024 + h * 64 + c2 * 16;
  *(int4*)&tile[jl][c2 * 16]     = *(const int4*)(src);
  *(int4*)&tile[jl][c2 * 16 + 8] = *(const int4*)(src + 8);
  __syncthreads();
  const int dl = t >> 2;
  union { u16 e[16]; int4 q[2]; } pk;
#pragma unroll
  for (int e = 0; e < 16; e++) pk.e[e] = tile[c2 * 16 + e][dl];
  u16* dst = vtg + (size_t)(bh * 64 + dl) * 1024 + j0 + c2 * 16;
  *(int4*)dst       = pk.q[0];
  *(int4*)(dst + 8) = pk.q[1];
}

// ---------------- bf16 GEMM: C[M][N] = A[M][K] * Bt[N][K]^T ----------------
// BM=256 BN=128 BK=64, 512 thr = 8 waves (4 wm x 2 wn, 64x64/wave), 3-buf LDS (144 KB),
// stage-first 2-ahead counted vmcnt(6), 1 barrier/iter, chunk-XOR swizzle (R5-verified),
// bijective XCD swizzle (grid must be 256). MODE: 0=f32+bias, 1=bf16, 2=bf16*QSC
template<int MODE>
__global__ __launch_bounds__(512) void gemm256p(const u16* __restrict__ A,
                                                const u16* __restrict__ Bt,
                                                void* __restrict__ Cout,
                                                const float* __restrict__ bias,
                                                int N, int K) {
  __shared__ __align__(16) u16 As[3][256 * 64];   // 96 KB
  __shared__ __align__(16) u16 Bs[3][128 * 64];   // 48 KB
  const int t = threadIdx.x, w = t >> 6, l = t & 63, g = l >> 4, m16 = l & 15;
  const int gx = N >> 7;
  const int bid = blockIdx.x;
  const int sw = (bid & 7) * 32 + (bid >> 3);     // XCD-contiguous (grid==256)
  const int bx = sw % gx, by = sw / gx;
  const int brow = by * 256, bcol = bx * 128;
  const int wm = w >> 1, wn = w & 1;
  const int nk = K >> 6;
  const int srow = t >> 3;
  const int sc   = t & 7;
  f32x4 acc[4][4] = {};

#define STAGE(ks, bsel)                                                              \
  {                                                                                  \
    int k0_ = (ks) << 6;                                                             \
    _Pragma("unroll")                                                                \
    for (int r = 0; r < 4; r++) {                                                    \
      int row = r * 64 + srow;                                                       \
      int cs = sc ^ (row & 7);                                                       \
      const u16* ga = A + (size_t)(brow + row) * K + k0_ + cs * 8;                   \
      __builtin_amdgcn_global_load_lds(                                              \
          (const __attribute__((address_space(1))) void*)ga,                         \
          (__attribute__((address_space(3))) void*)((char*)As + (bsel) * 32768 + r * 8192 + t * 16), \
          16, 0, 0);                                                                 \
    }                                                                                \
    _Pragma("unroll")                                                                \
    for (int r = 0; r < 2; r++) {                                                    \
      int row = r * 64 + srow;                                                       \
      int cs = sc ^ (row & 7);                                                       \
      const u16* gb = Bt + (size_t)(bcol + row) * K + k0_ + cs * 8;                  \
      __builtin_amdgcn_global_load_lds(                                              \
          (const __attribute__((address_space(1))) void*)gb,                         \
          (__attribute__((address_space(3))) void*)((char*)Bs + (bsel) * 16384 + r * 8192 + t * 16), \
          16, 0, 0);                                                                 \
    }                                                                                \
  }

  STAGE(0, 0);
  STAGE(1, 1);
  int cur = 0;
  for (int ks = 0; ks < nk; ++ks) {
    if (ks + 1 < nk) asm volatile("s_waitcnt vmcnt(6)" ::: "memory");
    else             asm volatile("s_waitcnt vmcnt(0)" ::: "memory");
    __builtin_amdgcn_s_barrier();
    if (ks + 2 < nk) {
      const int stg = (cur >= 1) ? cur - 1 : 2;   // (cur+2)%3 == (ks+2)%3
      STAGE(ks + 2, stg);
    }
    bf16x8 af[4][2], bfr[4][2];
#pragma unroll
    for (int m = 0; m < 4; m++) {
      const int row = wm * 64 + m * 16 + m16;
#pragma unroll
      for (int kh = 0; kh < 2; kh++)
        af[m][kh] = *(const bf16x8*)(&As[cur][row * 64 + (((kh * 4 + g) ^ (m16 & 7)) * 8)]);
    }
#pragma unroll
    for (int n = 0; n < 4; n++) {
      const int row = wn * 64 + n * 16 + m16;
#pragma unroll
      for (int kh = 0; kh < 2; kh++)
        bfr[n][kh] = *(const bf16x8*)(&Bs[cur][row * 64 + (((kh * 4 + g) ^ (m16 & 7)) * 8)]);
    }
    __builtin_amdgcn_s_setprio(1);
#pragma unroll
    for (int m = 0; m < 4; m++)
#pragma unroll
      for (int n = 0; n < 4; n++)
#pragma unroll
        for (int kh = 0; kh < 2; kh++)
          acc[m][n] = __builtin_amdgcn_mfma_f32_16x16x32_bf16(af[m][kh], bfr[n][kh], acc[m][n], 0, 0, 0);
    __builtin_amdgcn_s_setprio(0);
    cur = (cur == 2) ? 0 : cur + 1;
  }
#undef STAGE

#pragma unroll
  for (int m = 0; m < 4; m++) {
    int grow = brow + wm * 64 + m * 16 + g * 4;
#pragma unroll
    for (int n = 0; n < 4; n++) {
      int gcol = bcol + wn * 64 + n * 16 + m16;
#pragma unroll
      for (int r = 0; r < 4; r++) {
        size_t off = (size_t)(grow + r) * N + gcol;
        if (MODE == 0)      ((float*)Cout)[off] = acc[m][n][r] + bias[gcol];
        else if (MODE == 1) ((u16*)Cout)[off] = f2bf(acc[m][n][r]);
        else                ((u16*)Cout)[off] = f2bf(acc[m][n][r] * QSC);
      }
    }
  }
}

// ---------------- flash attention, 32x32x16 MFMA, in-register P, bias via C-in ----------------
// grid (16 qtiles, 16 heads, 4 batch), 256 thr = 4 waves, QBLK=128 (32 rows/wave), KVBLK=64
__global__ __launch_bounds__(256) void attn(const u16* __restrict__ Q, const u16* __restrict__ Kb,
                                            const u16* __restrict__ Vt_g,
                                            const float* __restrict__ biasg,
                                            u16* __restrict__ O) {
  const int qt = blockIdx.x, h = blockIdx.y, b = blockIdx.z;
  const int t = threadIdx.x, w = t >> 6, l = t & 63;
  const int i32 = l & 31, hi = l >> 5;
  const int bh = b * NH + h;

  __shared__ __align__(16) u16 Kl[2][4096];
  __shared__ __align__(16) u16 Vt[2][4096];
  __shared__ float biasl[NKV];

  for (int i = t; i < NKV; i += 256) biasl[i] = biasg[(size_t)b * NKV + i];

  const int qrow = qt * 128 + w * 32 + i32;
  const u16* qp = Q + (size_t)(b * NQ + qrow) * DIN + h * DH;
  bf16x8 qf[4];
#pragma unroll
  for (int c = 0; c < 4; c++) qf[c] = *(const bf16x8*)(qp + c * 16 + hi * 8);

  f32x16 oacc[2] = {};
  float lA = 0.f;

#define STAGE_K(j0, bsel)                                                     \
  {                                                                           \
    _Pragma("unroll")                                                         \
    for (int n = 0; n < 2; n++) {                                             \
      int j_ = n * 32 + (t >> 3);                                             \
      int c_ = (t & 7) ^ (j_ & 7);                                            \
      const u16* gk = Kb + (size_t)(b * NKV + (j0) + j_) * 2048 + h * DH + c_ * 8; \
      __builtin_amdgcn_global_load_lds(                                       \
          (const __attribute__((address_space(1))) void*)gk,                  \
          (__attribute__((address_space(3))) void*)((char*)Kl + (bsel) * 8192 + n * 4096 + t * 16), \
          16, 0, 0);                                                          \
    }                                                                         \
  }
#define STAGE_V(j0, bsel)                                                     \
  {                                                                           \
    _Pragma("unroll")                                                         \
    for (int n = 0; n < 2; n++) {                                             \
      int d_ = n * 32 + (t >> 3);                                             \
      int c_ = (t & 7) ^ (d_ & 7);                                            \
      const u16* gv = Vt_g + (size_t)(bh * 64 + d_) * 1024 + (j0) + c_ * 8;   \
      __builtin_amdgcn_global_load_lds(                                       \
          (const __attribute__((address_space(1))) void*)gv,                  \
          (__attribute__((address_space(3))) void*)((char*)Vt + (bsel) * 8192 + n * 4096 + t * 16), \
          16, 0, 0);                                                          \
    }                                                                         \
  }

  STAGE_K(0, 0);
  STAGE_V(0, 0);
  asm volatile("s_waitcnt vmcnt(0)" ::: "memory");
  __builtin_amdgcn_s_barrier();

  for (int it = 0; it < 16; ++it) {
    const int cur = it & 1, nxt = cur ^ 1;
    const int j0 = it * 64;
    if (it + 1 < 16) {
      STAGE_K(j0 + 64, nxt);
      STAGE_V(j0 + 64, nxt);
    }

    bf16x8 pa[4];
#pragma unroll
    for (int jt = 0; jt < 2; jt++) {
      float4 qb4[4];
#pragma unroll
      for (int a = 0; a < 4; a++)
        qb4[a] = *(const float4*)&biasl[j0 + jt * 32 + a * 8 + hi * 4];
      f32x16 s;
#pragma unroll
      for (int a = 0; a < 4; a++) {
        s[4 * a]     = qb4[a].x;
        s[4 * a + 1] = qb4[a].y;
        s[4 * a + 2] = qb4[a].z;
        s[4 * a + 3] = qb4[a].w;
      }
      __builtin_amdgcn_s_setprio(1);
#pragma unroll
      for (int c = 0; c < 4; c++) {
        bf16x8 kf = *(const bf16x8*)&Kl[cur][(jt * 32 + i32) * 64 + (((2 * c + hi) ^ (i32 & 7)) * 8)];
        s = __builtin_amdgcn_mfma_f32_32x32x16_bf16(kf, qf[c], s, 0, 0, 0);
      }
      __builtin_amdgcn_s_setprio(0);
      float p[16];
#pragma unroll
      for (int r = 0; r < 16; r++) p[r] = exp2a(s[r]);
#pragma unroll
      for (int r = 0; r < 16; r += 4)
        lA += ((p[r] + p[r + 1]) + (p[r + 2] + p[r + 3]));
      unsigned u[4][2];
#pragma unroll
      for (int a = 0; a < 4; a++) {
        u[a][0] = cvtpk(p[4 * a], p[4 * a + 1]);
        u[a][1] = cvtpk(p[4 * a + 2], p[4 * a + 3]);
      }
#pragma unroll
      for (int cc = 0; cc < 2; cc++) {
        unsigned s0 = hi ? u[2 * cc][0] : u[2 * cc + 1][0];
        unsigned s1 = hi ? u[2 * cc][1] : u[2 * cc + 1][1];
        unsigned r0 = __shfl_xor(s0, 32);
        unsigned r1 = __shfl_xor(s1, 32);
        union { unsigned uu[4]; bf16x8 v; } pw;
        pw.uu[0] = hi ? r0 : u[2 * cc][0];
        pw.uu[1] = hi ? r1 : u[2 * cc][1];
        pw.uu[2] = hi ? u[2 * cc + 1][0] : r0;
        pw.uu[3] = hi ? u[2 * cc + 1][1] : r1;
        pa[jt * 2 + cc] = pw.v;
      }
    }
    __builtin_amdgcn_s_setprio(1);
#pragma unroll
    for (int dt = 0; dt < 2; dt++) {
      const int d = dt * 32 + i32;
#pragma unroll
      for (int kc = 0; kc < 4; kc++) {
        bf16x8 vf = *(const bf16x8*)&Vt[cur][d * 64 + (((2 * kc + hi) ^ (i32 & 7)) * 8)];
        oacc[dt] = __builtin_amdgcn_mfma_f32_32x32x16_bf16(pa[kc], vf, oacc[dt], 0, 0, 0);
      }
    }
    __builtin_amdgcn_s_setprio(0);
    asm volatile("s_waitcnt vmcnt(0)" ::: "memory");
    __builtin_amdgcn_s_barrier();
  }
#undef STAGE_K
#undef STAGE_V

  lA += __shfl_xor(lA, 32);
  float inv = 1.f / lA;
  u16* op = O + (size_t)(b * NQ + qt * 128 + w * 32) * DIN + h * DH;
#pragma unroll
  for (int reg = 0; reg < 16; reg++) {
    const int irow = (reg & 3) + 8 * (reg >> 2) + 4 * hi;
    const float iv = __shfl(inv, irow);
#pragma unroll
    for (int dt = 0; dt < 2; dt++)
      op[(size_t)irow * DIN + dt * 32 + i32] = f2bf(oacc[dt][reg] * iv);
  }
}

// ---------------- launcher ----------------
extern "C" void kernel_launch(void* const* d_in, const int* in_sizes, int n_in,
                              void* d_out, int out_size, void* d_ws, size_t ws_size,
                              hipStream_t stream) {
  const float* x   = (const float*)d_in[0];
  const float* ctx = (const float*)d_in[1];
  const void*  mask = (const void*)d_in[2];
  const float* Wq  = (const float*)d_in[3];
  const float* Wk  = (const float*)d_in[4];
  const float* Wv  = (const float*)d_in[5];
  const float* Wo  = (const float*)d_in[6];
  const float* bo  = (const float*)d_in[7];
  float* out = (float*)d_out;

  char* ws = (char*)d_ws;
  u16* xb   = (u16*)(ws);                  // [8192][1024] bf16 (reused as ab)
  u16* cb   = (u16*)(ws + 16777216);       // [4096][768]
  u16* wqt  = (u16*)(ws + 23068672);       // [1024][1024]
  u16* wkv  = (u16*)(ws + 25165824);       // [2048][768]  (Wk^T | Wv^T)
  u16* wot  = (u16*)(ws + 28311552);       // [1024][1024]
  u16* qb   = (u16*)(ws + 30408704);       // [8192][1024]
  u16* kvb  = (u16*)(ws + 47185920);       // [4096][2048] (K | V)
  u16* vtg  = (u16*)(ws + 16777216);       // overlaps cb/wqt (dead by vtrans)
  float* biasg = (float*)(ws + 63963136);  // [4][1024]
  u16* ab   = xb;

  build_bias<<<1, 256, 0, stream>>>(mask, biasg);
  cvt_bf16<<<8192, 256, 0, stream>>>(x, xb, 8388608);
  cvt_bf16<<<3072, 256, 0, stream>>>(ctx, cb, 3145728);
  transpose_cvt<<<dim3(32, 32), 256, 0, stream>>>(Wq, wqt, 1024, 1024);
  transpose_cvt<<<dim3(32, 24), 256, 0, stream>>>(Wk, wkv, 768, 1024);
  transpose_cvt<<<dim3(32, 24), 256, 0, stream>>>(Wv, wkv + 1024 * 768, 768, 1024);
  transpose_cvt<<<dim3(32, 32), 256, 0, stream>>>(Wo, wot, 1024, 1024);

  gemm256p<2><<<256, 512, 0, stream>>>(xb, wqt, qb, nullptr, 1024, 1024);   // Q (pre-scaled)
  gemm256p<1><<<256, 512, 0, stream>>>(cb, wkv, kvb, nullptr, 2048, 768);   // K|V

  vtrans<<<dim3(16, 64), 256, 0, stream>>>(kvb, vtg);

  attn<<<dim3(16, 16, 4), 256, 0, stream>>>(qb, kvb, vtg, biasg, ab);

  gemm256p<0><<<256, 512, 0, stream>>>(ab, wot, out, bo, 1024, 1024);       // O + bias
}